// Round 1
// baseline (821.351 us; speedup 1.0000x reference)
//
#include <hip/hip_runtime.h>
#include <math.h>

#define NND 65536   // total nodes
#define NPER 512    // nodes per graph
#define NGR 128     // graphs (B)
#define DD 128      // feature dim
#define NED 524288  // edges

// ---------------- CSR build ----------------

__global__ __launch_bounds__(256) void init_kernel(int* __restrict__ counts,
                                                   int* __restrict__ mask) {
  int i = blockIdx.x * 256 + threadIdx.x;
  counts[i] = 0;
  mask[i] = 1;
}

__global__ __launch_bounds__(256) void hist_kernel(const int* __restrict__ ei,
                                                   int* __restrict__ counts) {
  int e = blockIdx.x * 256 + threadIdx.x;
  atomicAdd(&counts[ei[NED + e]], 1);
}

__global__ __launch_bounds__(1024) void scan_kernel(const int* __restrict__ counts,
                                                    int* __restrict__ off,
                                                    int* __restrict__ cursor) {
  __shared__ int part[1024];
  int t = threadIdx.x;
  int base = t * 64;
  int s = 0;
  for (int i = 0; i < 64; ++i) s += counts[base + i];
  part[t] = s;
  __syncthreads();
  for (int d = 1; d < 1024; d <<= 1) {
    int v = (t >= d) ? part[t - d] : 0;
    __syncthreads();
    part[t] += v;
    __syncthreads();
  }
  int run = (t == 0) ? 0 : part[t - 1];
  for (int i = 0; i < 64; ++i) {
    off[base + i] = run;
    cursor[base + i] = run;
    run += counts[base + i];
  }
  if (t == 1023) off[NND] = run;
}

__global__ __launch_bounds__(256) void scatter_kernel(const int* __restrict__ ei,
                                                      int* __restrict__ cursor,
                                                      int* __restrict__ ssrc) {
  int e = blockIdx.x * 256 + threadIdx.x;
  int dst = ei[NED + e];
  int pos = atomicAdd(&cursor[dst], 1);
  ssrc[pos] = ei[e];
}

// ---------------- weight transpose (wT[k][f] = w[f][k]) ----------------

__global__ __launch_bounds__(256) void transpose6_kernel(
    const float* __restrict__ w0, const float* __restrict__ w1,
    const float* __restrict__ w2, const float* __restrict__ w3,
    const float* __restrict__ w4, const float* __restrict__ w5,
    float* __restrict__ out) {
  const float* srcs[6] = {w0, w1, w2, w3, w4, w5};
  const float* s = srcs[blockIdx.x];
  float* d = out + (size_t)blockIdx.x * DD * DD;
  for (int i = threadIdx.x; i < DD * DD; i += 256) {
    int f = i >> 7, k = i & 127;
    d[k * DD + f] = s[i];
  }
}

// ---------------- mask-gated mean aggregation (one wave per dst) ----------------

__global__ __launch_bounds__(256) void agg_kernel(const float* __restrict__ x,
                                                  const int* __restrict__ mask,
                                                  const int* __restrict__ off,
                                                  const int* __restrict__ ssrc,
                                                  float* __restrict__ mean) {
  const int wave = threadIdx.x >> 6;
  const int lane = threadIdx.x & 63;
  const int dst = blockIdx.x * 4 + wave;
  float ax = 0.f, ay = 0.f;
  int deg = 0;
  if (mask[dst]) {
    const int beg = off[dst], end = off[dst + 1];
    for (int e = beg; e < end; ++e) {
      const int s = ssrc[e];
      if (mask[s]) {
        const float2 v = *(const float2*)(x + (size_t)s * DD + lane * 2);
        ax += v.x;
        ay += v.y;
        ++deg;
      }
    }
  }
  const float inv = 1.f / (float)max(deg, 1);
  float2 m;
  m.x = ax * inv;
  m.y = ay * inv;
  *(float2*)(mean + (size_t)dst * DD + lane * 2) = m;
}

// ---------------- fused SAGE GEMM: relu([mean|x] @ [wlT;wrT] + bl) ----------------
// BM=64, BN=128(full), BK=32, 256 threads, 4x8 microtile per thread.

#define BM 64
#define BK 32

__global__ __launch_bounds__(256) void gemm_kernel(const float* __restrict__ Amean,
                                                   const float* __restrict__ Ax,
                                                   const float* __restrict__ wlT,
                                                   const float* __restrict__ wrT,
                                                   const float* __restrict__ bias,
                                                   float* __restrict__ outp) {
  __shared__ float As[BK * BM];  // [k][row]
  __shared__ float Bs[BK * DD];  // [k][col]
  const int tid = threadIdx.x;
  const int tr = tid >> 4;  // 0..15
  const int tc = tid & 15;  // 0..15
  const int row0 = blockIdx.x * BM;

  float acc[4][8];
#pragma unroll
  for (int i = 0; i < 4; ++i)
#pragma unroll
    for (int j = 0; j < 8; ++j) acc[i][j] = 0.f;

  for (int kc = 0; kc < 8; ++kc) {
    const float* Asrc = (kc < 4) ? Amean : Ax;
    const int abase = (kc & 3) * BK;
// stage A: 64 rows x 32 k = 512 float4
#pragma unroll
    for (int i = 0; i < 2; ++i) {
      const int id = tid + i * 256;
      const int r = id >> 3;
      const int kk = (id & 7) << 2;
      const float4 v = *(const float4*)(Asrc + (size_t)(row0 + r) * DD + abase + kk);
      As[(kk + 0) * BM + r] = v.x;
      As[(kk + 1) * BM + r] = v.y;
      As[(kk + 2) * BM + r] = v.z;
      As[(kk + 3) * BM + r] = v.w;
    }
// stage B: 32 k x 128 cols = 1024 float4
#pragma unroll
    for (int i = 0; i < 4; ++i) {
      const int id = tid + i * 256;
      const int kr = id >> 5;
      const int f4 = (id & 31) << 2;
      const int gk = kc * BK + kr;
      const float* Bsrc = (gk < DD) ? (wlT + (size_t)gk * DD) : (wrT + (size_t)(gk - DD) * DD);
      *(float4*)(Bs + kr * DD + f4) = *(const float4*)(Bsrc + f4);
    }
    __syncthreads();
#pragma unroll
    for (int k = 0; k < BK; ++k) {
      const float4 a = *(const float4*)(As + k * BM + tr * 4);
      const float4 b0 = *(const float4*)(Bs + k * DD + tc * 8);
      const float4 b1 = *(const float4*)(Bs + k * DD + tc * 8 + 4);
      const float av[4] = {a.x, a.y, a.z, a.w};
      const float bv[8] = {b0.x, b0.y, b0.z, b0.w, b1.x, b1.y, b1.z, b1.w};
#pragma unroll
      for (int i = 0; i < 4; ++i)
#pragma unroll
        for (int j = 0; j < 8; ++j) acc[i][j] = fmaf(av[i], bv[j], acc[i][j]);
    }
    __syncthreads();
  }

  const int c0 = tc * 8;
  const float4 bb0 = *(const float4*)(bias + c0);
  const float4 bb1 = *(const float4*)(bias + c0 + 4);
#pragma unroll
  for (int i = 0; i < 4; ++i) {
    const int r = row0 + tr * 4 + i;
    float4 o0, o1;
    o0.x = fmaxf(acc[i][0] + bb0.x, 0.f);
    o0.y = fmaxf(acc[i][1] + bb0.y, 0.f);
    o0.z = fmaxf(acc[i][2] + bb0.z, 0.f);
    o0.w = fmaxf(acc[i][3] + bb0.w, 0.f);
    o1.x = fmaxf(acc[i][4] + bb1.x, 0.f);
    o1.y = fmaxf(acc[i][5] + bb1.y, 0.f);
    o1.z = fmaxf(acc[i][6] + bb1.z, 0.f);
    o1.w = fmaxf(acc[i][7] + bb1.w, 0.f);
    *(float4*)(outp + (size_t)r * DD + c0) = o0;
    *(float4*)(outp + (size_t)r * DD + c0 + 4) = o1;
  }
}

// ---------------- fused score + exact topk + tanh-scale + readout ----------------
// one block per graph, 512 threads (8 waves)

__global__ __launch_bounds__(512) void pool_kernel(float* __restrict__ h,
                                                   const float* __restrict__ pw,
                                                   int* __restrict__ mask,
                                                   float* __restrict__ zbuf,
                                                   const int kk, const float inv_k,
                                                   const int init) {
  __shared__ float s_sc[NPER];
  __shared__ float s_t[NPER];
  __shared__ unsigned char s_sel[NPER];
  __shared__ float s_red[8 * 128];
  __shared__ float s_norm;
  const int g = blockIdx.x;
  const int tid = threadIdx.x;
  const int wave = tid >> 6;
  const int lane = tid & 63;

  // 1/(||w|| + 1e-16)
  if (tid < 64) {
    const float v0 = pw[lane], v1 = pw[lane + 64];
    float p = v0 * v0 + v1 * v1;
#pragma unroll
    for (int o = 32; o > 0; o >>= 1) p += __shfl_down(p, o);
    if (lane == 0) s_norm = 1.f / (sqrtf(p) + 1e-16f);
  }
  __syncthreads();
  const float inv_norm = s_norm;

  // scores: wave w -> nodes [w*64, w*64+64)
  for (int t = 0; t < 64; ++t) {
    const int n = wave * 64 + t;
    const int node = g * NPER + n;
    const float2 xv = *(const float2*)(h + (size_t)node * DD + lane * 2);
    float p = xv.x * pw[lane * 2] + xv.y * pw[lane * 2 + 1];
#pragma unroll
    for (int o = 32; o > 0; o >>= 1) p += __shfl_down(p, o);
    if (lane == 0) s_sc[n] = mask[node] ? p * inv_norm : -INFINITY;
  }
  __syncthreads();

  // exact top-k via rank counting (stable tie-break by index, matches lax.top_k)
  {
    const int n = tid;
    const float s = s_sc[n];
    int rank = 0;
    for (int j = 0; j < NPER; ++j) {
      const float sj = s_sc[j];
      rank += (sj > s || (sj == s && j < n)) ? 1 : 0;
    }
    const int sel = (rank < kk) ? 1 : 0;
    s_sel[n] = (unsigned char)sel;
    s_t[n] = sel ? tanhf(s) : 0.f;
    mask[g * NPER + n] = sel;
  }
  __syncthreads();

  // apply tanh scaling to selected rows + max/sum readout
  const int fcol = tid & 127;
  const int nn = tid >> 7;  // 0..3, wave-uniform
  float pmax = -INFINITY;
  float psum = 0.f;
  for (int n = nn; n < NPER; n += 4) {
    if (s_sel[n]) {
      float* hp = h + ((size_t)(g * NPER + n)) * DD + fcol;
      const float v = *hp * s_t[n];
      *hp = v;
      pmax = fmaxf(pmax, v);
      psum += v;
    }
  }
  s_red[nn * 128 + fcol] = pmax;
  s_red[512 + nn * 128 + fcol] = psum;
  __syncthreads();
  if (tid < 128) {
    const float m = fmaxf(fmaxf(s_red[tid], s_red[128 + tid]),
                          fmaxf(s_red[256 + tid], s_red[384 + tid]));
    const float sm = s_red[512 + tid] + s_red[640 + tid] + s_red[768 + tid] + s_red[896 + tid];
    float* zb = zbuf + g * 256;
    if (init) {
      zb[tid] = m;
      zb[128 + tid] = sm * inv_k;
    } else {
      zb[tid] += m;
      zb[128 + tid] += sm * inv_k;
    }
  }
}

// ---------------- MLP head ----------------

__global__ __launch_bounds__(128) void mlp_kernel(const float* __restrict__ zbuf,
                                                  const float* __restrict__ w1,
                                                  const float* __restrict__ b1,
                                                  const float* __restrict__ w2,
                                                  const float* __restrict__ b2,
                                                  const float* __restrict__ w3,
                                                  const float* __restrict__ b3,
                                                  float* __restrict__ out) {
  __shared__ float z[256];
  __shared__ float h1[128];
  __shared__ float h2[64];
  const int g = blockIdx.x;
  const int t = threadIdx.x;
  z[t] = zbuf[g * 256 + t];
  z[t + 128] = zbuf[g * 256 + 128 + t];
  __syncthreads();
  float a = b1[t];
  for (int k = 0; k < 256; ++k) a = fmaf(z[k], w1[t * 256 + k], a);
  h1[t] = fmaxf(a, 0.f);
  __syncthreads();
  if (t < 64) {
    float a2 = b2[t];
    for (int k = 0; k < 128; ++k) a2 = fmaf(h1[k], w2[t * 128 + k], a2);
    h2[t] = fmaxf(a2, 0.f);
  }
  __syncthreads();
  if (t == 0) {
    float a3 = b3[0];
    for (int k = 0; k < 64; ++k) a3 = fmaf(h2[k], w3[k], a3);
    out[g] = 1.f / (1.f + expf(-a3));
  }
}

// ---------------- launch ----------------

extern "C" void kernel_launch(void* const* d_in, const int* in_sizes, int n_in,
                              void* d_out, int out_size, void* d_ws, size_t ws_size,
                              hipStream_t stream) {
  (void)in_sizes; (void)n_in; (void)out_size; (void)ws_size;
  const float* x_in = (const float*)d_in[0];
  const int* ei = (const int*)d_in[1];
  const float* wl[3] = {(const float*)d_in[2], (const float*)d_in[6], (const float*)d_in[10]};
  const float* cbl[3] = {(const float*)d_in[3], (const float*)d_in[7], (const float*)d_in[11]};
  const float* wr[3] = {(const float*)d_in[4], (const float*)d_in[8], (const float*)d_in[12]};
  const float* pw[3] = {(const float*)d_in[5], (const float*)d_in[9], (const float*)d_in[13]};
  const float* l1w = (const float*)d_in[14];
  const float* l1b = (const float*)d_in[15];
  const float* l2w = (const float*)d_in[16];
  const float* l2b = (const float*)d_in[17];
  const float* l3w = (const float*)d_in[18];
  const float* l3b = (const float*)d_in[19];
  float* out = (float*)d_out;

  char* w = (char*)d_ws;
  int* counts = (int*)(w + 0 * (1 << 20));
  int* off = (int*)(w + 1 * (1 << 20));
  int* cursor = (int*)(w + 2 * (1 << 20));
  int* mask = (int*)(w + 3 * (1 << 20));
  float* zbuf = (float*)(w + 4 * (1 << 20));
  float* wT = (float*)(w + 5 * (1 << 20));   // 6 * 64KB
  int* ssrc = (int*)(w + 6 * (1 << 20));     // 2MB
  float* mean = (float*)(w + (size_t)8 * (1 << 20));   // 32MB
  float* hA = (float*)(w + (size_t)40 * (1 << 20));    // 32MB
  float* hB = (float*)(w + (size_t)72 * (1 << 20));    // 32MB  (total 104MB)

  init_kernel<<<NND / 256, 256, 0, stream>>>(counts, mask);
  hist_kernel<<<NED / 256, 256, 0, stream>>>(ei, counts);
  scan_kernel<<<1, 1024, 0, stream>>>(counts, off, cursor);
  scatter_kernel<<<NED / 256, 256, 0, stream>>>(ei, cursor, ssrc);
  transpose6_kernel<<<6, 256, 0, stream>>>(wl[0], wr[0], wl[1], wr[1], wl[2], wr[2], wT);

  const int ks[3] = {410, 328, 263};
  const float* xl = x_in;
  float* houts[3] = {hA, hB, hA};
  for (int l = 0; l < 3; ++l) {
    float* hout = houts[l];
    agg_kernel<<<NND / 4, 256, 0, stream>>>(xl, mask, off, ssrc, mean);
    gemm_kernel<<<NND / BM, 256, 0, stream>>>(mean, xl, wT + (size_t)(2 * l) * DD * DD,
                                              wT + (size_t)(2 * l + 1) * DD * DD, cbl[l], hout);
    pool_kernel<<<NGR, 512, 0, stream>>>(hout, pw[l], mask, zbuf, ks[l], 1.f / (float)ks[l],
                                         (l == 0) ? 1 : 0);
    xl = hout;
  }
  mlp_kernel<<<NGR, 128, 0, stream>>>(zbuf, l1w, l1b, l2w, l2b, l3w, l3b, out);
}